// Round 8
// baseline (576.691 us; speedup 1.0000x reference)
//
#include <hip/hip_runtime.h>
#include <hip/hip_bf16.h>

#define NN 768
#define CSD 384
#define CZD 128
#define HD 12
#define DOUT 2112
#define II 2
#define ALS 772                      /* padded a_l row stride (floats) */
#define WBS 132                      /* padded wbT row stride (floats) */

#define SCALE_SINGLE 0.25f
#define SCALE_FRAME (-0.11785113019775793f)   /* -1/sqrt(72) */

__device__ __forceinline__ float dot4f(float4 a, float4 b){
    return fmaf(a.x,b.x, fmaf(a.y,b.y, fmaf(a.z,b.z, a.w*b.w)));
}

// ---------------- K1: projections + frame apply, II=2 residues per block ----------------
__global__ __launch_bounds__(384) void k_proj(
    const float* __restrict__ s, const float* __restrict__ R, const float* __restrict__ tv,
    const float* __restrict__ Wq, const float* __restrict__ Wk, const float* __restrict__ Wv,
    const float* __restrict__ Wqp, const float* __restrict__ Wkp, const float* __restrict__ Wvp,
    float* __restrict__ q, float* __restrict__ k, float* __restrict__ v,
    float* __restrict__ gq, float* __restrict__ gk, float* __restrict__ gv,
    float* __restrict__ sqq, float* __restrict__ sqk)
{
    __shared__ float s_l[II*CSD];
    __shared__ float praw[II][576];
    __shared__ float sq_pt[II][96];
    int i0 = blockIdx.x * II, t = threadIdx.x;
    if (t < II*CSD/4){
        const float4* s4 = (const float4*)(s + (size_t)i0*CSD);
        ((float4*)s_l)[t] = s4[t];
    }
    __syncthreads();

    int cols[3] = {t, t+384, t+768};
    const float* Wp[3]; int st[3], lc[3];
    #pragma unroll
    for (int m=0;m<3;m++){
        int c = cols[m];
        if (c < 192){ Wp[m]=Wq;  st[m]=192; lc[m]=c; }
        else if (c < 384){ Wp[m]=Wk;  st[m]=192; lc[m]=c-192; }
        else if (c < 576){ Wp[m]=Wv;  st[m]=192; lc[m]=c-384; }
        else if (c < 720){ Wp[m]=Wqp; st[m]=144; lc[m]=c-576; }
        else if (c < 864){ Wp[m]=Wkp; st[m]=144; lc[m]=c-720; }
        else { Wp[m]=Wvp; st[m]=288; lc[m]=c-864; }
    }
    float acc[3][II];
    #pragma unroll
    for (int m=0;m<3;m++)
        #pragma unroll
        for (int ii=0;ii<II;ii++) acc[m][ii]=0.f;

    #pragma unroll 4
    for (int r=0;r<CSD;r++){
        float w0 = Wp[0][(size_t)r*st[0]+lc[0]];
        float w1 = Wp[1][(size_t)r*st[1]+lc[1]];
        float w2 = Wp[2][(size_t)r*st[2]+lc[2]];
        #pragma unroll
        for (int ii=0;ii<II;ii++){
            float sv = s_l[ii*CSD + r];
            acc[0][ii] = fmaf(sv, w0, acc[0][ii]);
            acc[1][ii] = fmaf(sv, w1, acc[1][ii]);
            acc[2][ii] = fmaf(sv, w2, acc[2][ii]);
        }
    }
    #pragma unroll
    for (int m=0;m<3;m++){
        int c = cols[m];
        #pragma unroll
        for (int ii=0;ii<II;ii++){
            float val = acc[m][ii];
            size_t i = i0 + ii;
            if (c < 192) q[i*192 + c] = val;
            else if (c < 384) k[i*192 + (c-192)] = val;
            else if (c < 576) v[i*192 + (c-384)] = val;
            else praw[ii][c-576] = val;
        }
    }
    __syncthreads();

    if (t < 192){
        #pragma unroll
        for (int ii=0;ii<II;ii++){
            size_t i = i0 + ii;
            const float* Ri = R + i*9;
            float R00=Ri[0],R01=Ri[1],R02=Ri[2];
            float R10=Ri[3],R11=Ri[4],R12=Ri[5];
            float R20=Ri[6],R21=Ri[7],R22=Ri[8];
            float t0=tv[i*3+0],t1=tv[i*3+1],t2=tv[i*3+2];
            int src; float* dst; int sqslot=-1;
            if (t < 48){ src = t*3; dst = gq + i*144 + t*3; sqslot = t; }
            else if (t < 96){ int u=t-48; src = 144+u*3; dst = gk + i*144 + u*3; sqslot = 48+u; }
            else { int u=t-96; src = 288+u*3; dst = gv + i*288 + u*3; }
            float x=praw[ii][src], y=praw[ii][src+1], zc=praw[ii][src+2];
            float g0 = fmaf(R00,x, fmaf(R01,y, fmaf(R02,zc, t0)));
            float g1 = fmaf(R10,x, fmaf(R11,y, fmaf(R12,zc, t1)));
            float g2 = fmaf(R20,x, fmaf(R21,y, fmaf(R22,zc, t2)));
            dst[0]=g0; dst[1]=g1; dst[2]=g2;
            if (sqslot >= 0) sq_pt[ii][sqslot] = g0*g0 + g1*g1 + g2*g2;
        }
    }
    __syncthreads();
    if (t < II*HD){
        int ii = t / HD, h = t % HD;
        float s1 = sq_pt[ii][h*4]+sq_pt[ii][h*4+1]+sq_pt[ii][h*4+2]+sq_pt[ii][h*4+3];
        float s2 = sq_pt[ii][48+h*4]+sq_pt[ii][48+h*4+1]+sq_pt[ii][48+h*4+2]+sq_pt[ii][48+h*4+3];
        sqq[(size_t)(i0+ii)*HD + h] = s1;
        sqk[(size_t)(i0+ii)*HD + h] = s2;
    }
}

// ---------------- K2: fused IPA, DS-minimized ----------------
// 512 threads = 8 waves. Roles:
//   wave 0       : pair logits (row-pair {r,r+16} x head-triple per lane), writes a_l
//   wave 1       : idle phase A / o_z phase B
//   waves 2-5    : pure staging (counted vmcnt, depth-3, 4 buffers)
//   waves 6-7    : single+frame from global (reg-preloaded q/gq), RMW into a_l 1 tile behind
// BARX = s_waitcnt lgkmcnt(0) + s_barrier: the lgkmcnt(0) is REQUIRED for the
// pair wave's ds_writes to be visible to the RMW waves (raw s_barrier does not
// drain the DS queue). vmcnt stays counted (staging pipeline unaffected).
__global__ __launch_bounds__(512) void k_ipa(
    const float* __restrict__ z, const float* __restrict__ Wb, const float* __restrict__ scale_head,
    const float* __restrict__ q, const float* __restrict__ k,
    const float* __restrict__ gq, const float* __restrict__ gk,
    const float* __restrict__ sqq, const float* __restrict__ sqk,
    const float* __restrict__ v, const float* __restrict__ gv,
    const float* __restrict__ R, const float* __restrict__ tv,
    float* __restrict__ att)
{
    __shared__ float ztile[4][32][CZD];   // 64KB staging buffers
    __shared__ float wbT[HD*WBS];         // padded [h][c]
    __shared__ float a_l[HD*ALS];         // padded logits -> attention
    __shared__ float so_l[288];

    int i = blockIdx.x, t = threadIdx.x;
    int wave = t >> 6, lane = t & 63;
    bool stg = (t >= 128 && t < 384);
    int ts = t - 128;

    for (int idx=t; idx<HD*CZD; idx+=512){
        int h = idx >> 7, c = idx & 127;
        wbT[h*WBS + c] = Wb[(size_t)c*HD + h];
    }

    const char* zi = (const char*)(z + (size_t)i*NN*CZD);
    float* zbase = &ztile[0][0][0];

#define WAITV(N) asm volatile("s_waitcnt vmcnt(" #N ")" ::: "memory")
#define BARX() do{ asm volatile("s_waitcnt lgkmcnt(0)" ::: "memory"); __builtin_amdgcn_s_barrier(); asm volatile("" ::: "memory"); }while(0)

#define STAGEA(JT, BUF) do { \
    const char* _zb = zi + (size_t)(JT)*16384; \
    char* _lb = (char*)zbase + (size_t)(BUF)*16384; \
    _Pragma("unroll") \
    for (int _m=0;_m<4;_m++){ \
        int _d = ts*16 + _m*4096; \
        int _j = _d >> 9; \
        int _b = _d & 511; \
        int _sb = _b ^ ((_j & 31) << 4); \
        __builtin_amdgcn_global_load_lds((const __attribute__((address_space(1))) void*)(_zb + (size_t)_j*512 + _sb), \
            (__attribute__((address_space(3))) void*)(_lb + _d), 16, 0, 0); \
    } \
  } while(0)

#define STAGEB(JT, BUF) do { \
    const char* _zb = zi + (size_t)(JT)*16384; \
    char* _lb = (char*)zbase + (size_t)(BUF)*16384; \
    _Pragma("unroll") \
    for (int _m=0;_m<4;_m++){ \
        int _d = ts*16 + _m*4096; \
        __builtin_amdgcn_global_load_lds((const __attribute__((address_space(1))) void*)(_zb + _d), \
            (__attribute__((address_space(3))) void*)(_lb + _d), 16, 0, 0); \
    } \
  } while(0)

    // role register state
    int rgrp = lane & 15, gp = lane >> 4;             // pair wave
    int rS = lane & 31, gS = (wave-6)*2 + (lane>>5);  // SF waves
    float4 qv[3][4]; float4 gqv[3][3]; float sqq3[3], sp3[3];
    if (wave >= 6){
        #pragma unroll
        for (int hs=0; hs<3; ++hs){
            int h = gS*3 + hs;
            const float4* qp = (const float4*)(q + (size_t)i*192 + h*16);
            qv[hs][0]=qp[0]; qv[hs][1]=qp[1]; qv[hs][2]=qp[2]; qv[hs][3]=qp[3];
            const float4* gp4 = (const float4*)(gq + (size_t)i*144 + h*12);
            gqv[hs][0]=gp4[0]; gqv[hs][1]=gp4[1]; gqv[hs][2]=gp4[2];
            sqq3[hs] = sqq[(size_t)i*HD + h];
            float shv = scale_head[h];
            float sp = (shv > 20.f) ? shv : log1pf(__expf(shv));
            sp3[hs] = SCALE_FRAME * sp;
        }
    }

    __syncthreads();   // wbT published
    if (stg){ STAGEA(0,0); STAGEA(1,1); STAGEA(2,2); }

    float SFp0=0.f, SFp1=0.f, SFp2=0.f;

    // ---------------- phase A ----------------
    for (int jt=0; jt<24; ++jt){
        if (stg){
            if (jt < 22) WAITV(8);
            else if (jt == 22) WAITV(4);
            else WAITV(0);
        }
        BARX();
        if (stg && jt+3 < 24) STAGEA(jt+3, (jt+3)&3);
        if (wave == 0){
            const char* zrow0 = (const char*)zbase + (size_t)(jt&3)*16384 + (size_t)rgrp*512;
            const char* zrow1 = zrow0 + 16*512;
            int x0 = rgrp<<4, x1 = (rgrp+16)<<4;
            const float4* wbg = (const float4*)(wbT + gp*3*WBS);
            float L00=0.f,L01=0.f,L02=0.f,L10=0.f,L11=0.f,L12=0.f;
            #pragma unroll 8
            for (int c4=0; c4<32; ++c4){
                float4 z0 = *(const float4*)(zrow0 + ((c4*16) ^ x0));
                float4 z1 = *(const float4*)(zrow1 + ((c4*16) ^ x1));
                float4 w0 = wbg[c4];
                float4 w1 = wbg[33 + c4];
                float4 w2 = wbg[66 + c4];
                L00 += dot4f(z0,w0); L01 += dot4f(z0,w1); L02 += dot4f(z0,w2);
                L10 += dot4f(z1,w0); L11 += dot4f(z1,w1); L12 += dot4f(z1,w2);
            }
            int j0 = jt*32 + rgrp;
            a_l[(gp*3+0)*ALS + j0] = L00;  a_l[(gp*3+0)*ALS + j0+16] = L10;
            a_l[(gp*3+1)*ALS + j0] = L01;  a_l[(gp*3+1)*ALS + j0+16] = L11;
            a_l[(gp*3+2)*ALS + j0] = L02;  a_l[(gp*3+2)*ALS + j0+16] = L12;
        } else if (wave >= 6){
            // RMW previous tile (pair writes from jt-1 made visible by BARX's lgkmcnt(0)+barrier)
            if (jt > 0){
                int jp = (jt-1)*32 + rS;
                a_l[(gS*3+0)*ALS + jp] += SFp0;
                a_l[(gS*3+1)*ALS + jp] += SFp1;
                a_l[(gS*3+2)*ALS + jp] += SFp2;
            }
            int jg = jt*32 + rS;
            const float4* kp  = (const float4*)(k  + (size_t)jg*192);
            const float4* gkp = (const float4*)(gk + (size_t)jg*144);
            float sf[3];
            #pragma unroll
            for (int hs=0; hs<3; ++hs){
                int h = gS*3 + hs;
                float sng = dot4f(qv[hs][0], kp[h*4+0]) + dot4f(qv[hs][1], kp[h*4+1])
                          + dot4f(qv[hs][2], kp[h*4+2]) + dot4f(qv[hs][3], kp[h*4+3]);
                float fdot = dot4f(gqv[hs][0], gkp[h*3+0]) + dot4f(gqv[hs][1], gkp[h*3+1])
                           + dot4f(gqv[hs][2], gkp[h*3+2]);
                float d2 = sqq3[hs] + sqk[(size_t)jg*HD + h] - 2.0f*fdot;
                sf[hs] = fmaf(SCALE_SINGLE, sng, sp3[hs]*d2);
            }
            SFp0 = sf[0]; SFp1 = sf[1]; SFp2 = sf[2];
        }
    }
    // barrier before the final RMW: pair wave's tile-23 writes must be published
    BARX();
    if (wave >= 6){    // RMW last tile
        int jp = 23*32 + rS;
        a_l[(gS*3+0)*ALS + jp] += SFp0;
        a_l[(gS*3+1)*ALS + jp] += SFp1;
        a_l[(gS*3+2)*ALS + jp] += SFp2;
    }
    __syncthreads();

    // softmax: waves 0-5, 2 heads each
    if (wave < 6){
        #pragma unroll
        for (int hh=0; hh<2; ++hh){
            int h = wave*2 + hh;
            float4* row4 = (float4*)(a_l + h*ALS);
            float4 vls[3];
            #pragma unroll
            for (int qq=0; qq<3; ++qq) vls[qq] = row4[lane + 64*qq];
            float m = -1e30f;
            #pragma unroll
            for (int qq=0; qq<3; ++qq){
                m = fmaxf(m, fmaxf(fmaxf(vls[qq].x, vls[qq].y), fmaxf(vls[qq].z, vls[qq].w)));
            }
            #pragma unroll
            for (int off=32; off; off>>=1) m = fmaxf(m, __shfl_xor(m, off));
            float ssum = 0.f;
            #pragma unroll
            for (int qq=0; qq<3; ++qq){
                vls[qq].x = __expf(vls[qq].x - m); vls[qq].y = __expf(vls[qq].y - m);
                vls[qq].z = __expf(vls[qq].z - m); vls[qq].w = __expf(vls[qq].w - m);
                ssum += (vls[qq].x + vls[qq].y) + (vls[qq].z + vls[qq].w);
            }
            #pragma unroll
            for (int off=32; off; off>>=1) ssum += __shfl_xor(ssum, off);
            float inv = 1.0f/ssum;
            #pragma unroll
            for (int qq=0; qq<3; ++qq){
                vls[qq].x *= inv; vls[qq].y *= inv; vls[qq].z *= inv; vls[qq].w *= inv;
                row4[lane + 64*qq] = vls[qq];
            }
        }
    }
    __syncthreads();

    // ---------------- phase B ----------------
    if (stg){ STAGEB(0,0); STAGEB(1,1); STAGEB(2,2); }

    int c4 = lane & 31;
    int hgz = wave*2 + (lane>>5);          // waves 0-1 -> head-triples 0..3
    float4 az0={0,0,0,0}, az1={0,0,0,0}, az2={0,0,0,0};
    float4 accs = {0,0,0,0};
    const float4* gsrc = nullptr; int gstride = 0; int hso = 0;
    if (t >= 384 && t < 432){ int u=t-384; hso = u>>2; gsrc = (const float4*)v  + hso*4 + (u&3); gstride = 48; }
    else if (t >= 432 && t < 504){ int u=t-432; hso = u/6;  gsrc = (const float4*)gv + hso*6 + (u%6); gstride = 72; }

    for (int jt=0; jt<24; ++jt){
        if (stg){
            if (jt < 22) WAITV(8);
            else if (jt == 22) WAITV(4);
            else WAITV(0);
        }
        BARX();
        if (stg && jt+3 < 24) STAGEB(jt+3, (jt+3)&3);
        if (wave < 2){
            const float4* zt4 = (const float4*)(zbase + (size_t)(jt&3)*4096);
            const float4* arow = (const float4*)a_l;
            int h0 = hgz*3;
            #pragma unroll
            for (int jq=0; jq<8; ++jq){
                float4 a0 = arow[(h0+0)*(ALS/4) + jt*8 + jq];
                float4 a1 = arow[(h0+1)*(ALS/4) + jt*8 + jq];
                float4 a2 = arow[(h0+2)*(ALS/4) + jt*8 + jq];
                #pragma unroll
                for (int u=0; u<4; ++u){
                    float4 zv = zt4[(jq*4+u)*32 + c4];
                    float w0 = ((const float*)&a0)[u];
                    float w1 = ((const float*)&a1)[u];
                    float w2 = ((const float*)&a2)[u];
                    az0.x = fmaf(w0, zv.x, az0.x); az0.y = fmaf(w0, zv.y, az0.y);
                    az0.z = fmaf(w0, zv.z, az0.z); az0.w = fmaf(w0, zv.w, az0.w);
                    az1.x = fmaf(w1, zv.x, az1.x); az1.y = fmaf(w1, zv.y, az1.y);
                    az1.z = fmaf(w1, zv.z, az1.z); az1.w = fmaf(w1, zv.w, az1.w);
                    az2.x = fmaf(w2, zv.x, az2.x); az2.y = fmaf(w2, zv.y, az2.y);
                    az2.z = fmaf(w2, zv.z, az2.z); az2.w = fmaf(w2, zv.w, az2.w);
                }
            }
        } else if (t >= 384 && t < 504){
            const float* arow = a_l + hso*ALS;
            #pragma unroll
            for (int jj=0; jj<32; ++jj){
                int j = jt*32 + jj;
                float aw = arow[j];
                float4 sv = gsrc[(size_t)j*gstride];
                accs.x = fmaf(aw, sv.x, accs.x);
                accs.y = fmaf(aw, sv.y, accs.y);
                accs.z = fmaf(aw, sv.z, accs.z);
                accs.w = fmaf(aw, sv.w, accs.w);
            }
        }
    }

    // epilogue
    if (wave < 2){
        int h0 = hgz*3;
        *(float4*)(att + (size_t)i*DOUT + 192 + (h0+0)*128 + c4*4) = az0;
        *(float4*)(att + (size_t)i*DOUT + 192 + (h0+1)*128 + c4*4) = az1;
        *(float4*)(att + (size_t)i*DOUT + 192 + (h0+2)*128 + c4*4) = az2;
    } else if (t >= 384 && t < 432){
        int u = t-384;
        ((float4*)(att + (size_t)i*DOUT))[u] = accs;
    } else if (t >= 432 && t < 504){
        int u = t-432;
        ((float4*)so_l)[u] = accs;
    }
    __syncthreads();
    if (t < 96){
        int h = t >> 3, p = t & 7;
        float d0 = so_l[h*24+p*3+0] - tv[(size_t)i*3+0];
        float d1 = so_l[h*24+p*3+1] - tv[(size_t)i*3+1];
        float d2 = so_l[h*24+p*3+2] - tv[(size_t)i*3+2];
        const float* Ri = R + (size_t)i*9;
        float l0 = fmaf(Ri[0],d0, fmaf(Ri[3],d1, Ri[6]*d2));
        float l1 = fmaf(Ri[1],d0, fmaf(Ri[4],d1, Ri[7]*d2));
        float l2 = fmaf(Ri[2],d0, fmaf(Ri[5],d1, Ri[8]*d2));
        size_t base = (size_t)i*DOUT;
        att[base + 1728 + p*36 + h*3 + 0] = l0;
        att[base + 1728 + p*36 + h*3 + 1] = l1;
        att[base + 1728 + p*36 + h*3 + 2] = l2;
        att[base + 2016 + p*12 + h] = sqrtf(l0*l0 + l1*l1 + l2*l2);
    }
#undef STAGEA
#undef STAGEB
#undef WAITV
#undef BARX
}

// ---------------- K4: final projection att @ Wout + bout ----------------
#define ROWS4 2
__global__ __launch_bounds__(384) void k_final(
    const float* __restrict__ att, const float* __restrict__ Wout, const float* __restrict__ bout,
    float* __restrict__ out)
{
    __shared__ float att_l[ROWS4*DOUT];
    int ib = blockIdx.x * ROWS4, t = threadIdx.x;
    for (int idx=t; idx<ROWS4*DOUT; idx+=384){
        att_l[idx] = att[(size_t)ib*DOUT + idx];
    }
    __syncthreads();
    float a0=0.f,a1=0.f,a2=0.f,a3=0.f;
    float b0=0.f,b1=0.f,b2=0.f,b3=0.f;
    #pragma unroll 4
    for (int d=0; d<DOUT; d+=4){
        float w0 = Wout[(size_t)(d+0)*CSD + t];
        float w1 = Wout[(size_t)(d+1)*CSD + t];
        float w2 = Wout[(size_t)(d+2)*CSD + t];
        float w3 = Wout[(size_t)(d+3)*CSD + t];
        a0 = fmaf(att_l[d+0], w0, a0);
        a1 = fmaf(att_l[d+1], w1, a1);
        a2 = fmaf(att_l[d+2], w2, a2);
        a3 = fmaf(att_l[d+3], w3, a3);
        b0 = fmaf(att_l[DOUT+d+0], w0, b0);
        b1 = fmaf(att_l[DOUT+d+1], w1, b1);
        b2 = fmaf(att_l[DOUT+d+2], w2, b2);
        b3 = fmaf(att_l[DOUT+d+3], w3, b3);
    }
    float bb = bout[t];
    out[(size_t)ib*CSD + t]     = bb + ((a0+a1)+(a2+a3));
    out[(size_t)(ib+1)*CSD + t] = bb + ((b0+b1)+(b2+b3));
}

extern "C" void kernel_launch(void* const* d_in, const int* in_sizes, int n_in,
                              void* d_out, int out_size, void* d_ws, size_t ws_size,
                              hipStream_t stream)
{
    const float* s   = (const float*)d_in[0];
    const float* z   = (const float*)d_in[1];
    const float* R   = (const float*)d_in[2];
    const float* tv  = (const float*)d_in[3];
    const float* Wq  = (const float*)d_in[4];
    const float* Wk  = (const float*)d_in[5];
    const float* Wv  = (const float*)d_in[6];
    const float* Wqp = (const float*)d_in[7];
    const float* Wkp = (const float*)d_in[8];
    const float* Wvp = (const float*)d_in[9];
    const float* Wb  = (const float*)d_in[10];
    const float* Wout= (const float*)d_in[11];
    const float* bout= (const float*)d_in[12];
    const float* sh  = (const float*)d_in[13];

    float* ws  = (float*)d_ws;
    float* q_  = ws;                 // 768*192
    float* k_  = q_  + 147456;       // 768*192
    float* v_  = k_  + 147456;       // 768*192
    float* gq_ = v_  + 147456;       // 768*144
    float* gk_ = gq_ + 110592;       // 768*144
    float* gv_ = gk_ + 110592;       // 768*288
    float* sqq_= gv_ + 221184;       // 768*12
    float* sqk_= sqq_ + 9216;        // 768*12
    float* att_= sqk_ + 9216;        // 768*2112
    float* out = (float*)d_out;

    hipLaunchKernelGGL(k_proj,  dim3(NN/II), dim3(384), 0, stream,
                       s,R,tv,Wq,Wk,Wv,Wqp,Wkp,Wvp, q_,k_,v_,gq_,gk_,gv_,sqq_,sqk_);
    hipLaunchKernelGGL(k_ipa,   dim3(NN),    dim3(512), 0, stream,
                       z,Wb,sh,q_,k_,gq_,gk_,sqq_,sqk_, v_,gv_,R,tv, att_);
    hipLaunchKernelGGL(k_final, dim3(NN/ROWS4), dim3(384), 0, stream,
                       att_,Wout,bout, out);
}